// Round 3
// baseline (167.940 us; speedup 1.0000x reference)
//
#include <hip/hip_runtime.h>
#include <math.h>

#define MDIM 512
#define NDIM 512
#define KDIM 512

#define BM 64
#define BN 64
#define BK 32
#define LSTR 68   // padded LDS row stride (floats); 272B rows keep b128 16B-aligned
#define KSPLIT 16 // K-chunk = 512/16 = 32 = BK (single stage+compute per block)

// SC encoding collapses to: ax = m*2^e (frexp), q = floor(m*L),
// v = sign * 2^(e+shAdj) with shAdj = -log2(L) for A, 0 for B. dataWidth cancels.
// min(q1,q2) == thermometer AND-popcount (both sequences are thermometer codes).
__device__ __forceinline__ void sc_encode(float x, int shAdj, float Lf,
                                          float& v, float& q) {
    float ax = fabsf(x);
    v = 0.0f; q = 0.0f;
    if (ax > 0.0f) {
        int e;
        float m = frexpf(ax, &e);          // ax = m * 2^e, m in [0.5,1)
        q = floorf(m * Lf);                // exact: m*L is an exact f32 product
        v = ldexpf((x > 0.0f) ? 1.0f : -1.0f, e + shAdj);
    }
}

// Fused: SC-encode during staging + min-GEMM (approx) + f32 GEMM (exact).
// Grid (N/BN, M/BM, KSPLIT); block 256; 4x4 micro-tile; atomic split-K epilogue.
__global__ __launch_bounds__(256) void sc_gemm(
        const float* __restrict__ t1, const float* __restrict__ t2,
        float* __restrict__ out, float Lf, int logL) {
    __shared__ __align__(16) float As_v[BK][LSTR];
    __shared__ __align__(16) float As_q[BK][LSTR];
    __shared__ __align__(16) float As_t[BK][LSTR];
    __shared__ __align__(16) float Bs_v[BK][LSTR];
    __shared__ __align__(16) float Bs_q[BK][LSTR];
    __shared__ __align__(16) float Bs_t[BK][LSTR];

    const int tid = threadIdx.x;
    const int tx = tid & 15;
    const int ty = tid >> 4;
    const int n0 = blockIdx.x * BN;
    const int m0 = blockIdx.y * BM;
    const int kk0 = blockIdx.z * BK;

    // stage A tile (64 m-rows x 32 k), encode inline, transpose into LDS [k][m]
    #pragma unroll
    for (int ff = 0; ff < 2; ++ff) {
        int f = tid + ff * 256;            // 512 float4s
        int row = f >> 3;                  // 0..63
        int c4  = (f & 7) << 2;            // k offset 0..28
        float4 t = *(const float4*)(t1 + (m0 + row) * KDIM + kk0 + c4);
        const float* tp = &t.x;
        #pragma unroll
        for (int d = 0; d < 4; ++d) {
            float v, q;
            sc_encode(tp[d], -logL, Lf, v, q);
            As_v[c4 + d][row] = v;
            As_q[c4 + d][row] = q;
            As_t[c4 + d][row] = tp[d];
        }
    }
    // stage B tile (32 k x 64 n), encode inline, natural layout [k][n]
    #pragma unroll
    for (int ff = 0; ff < 2; ++ff) {
        int f = tid + ff * 256;
        int rowk = f >> 4;                 // 0..31
        int c4   = (f & 15) << 2;          // n offset 0..60
        float4 t = *(const float4*)(t2 + (kk0 + rowk) * NDIM + n0 + c4);
        float4 v4, q4;
        float* vp = &v4.x; float* qp = &q4.x; const float* tp = &t.x;
        #pragma unroll
        for (int d = 0; d < 4; ++d) sc_encode(tp[d], 0, Lf, vp[d], qp[d]);
        *(float4*)&Bs_v[rowk][c4] = v4;
        *(float4*)&Bs_q[rowk][c4] = q4;
        *(float4*)&Bs_t[rowk][c4] = t;
    }
    __syncthreads();

    float acc[4][4] = {};
    float acce[4][4] = {};

    #pragma unroll 8
    for (int kk = 0; kk < BK; ++kk) {
        float av[4], aq[4], at[4], bv[4], bq[4], bt[4];
        *(float4*)av = *(const float4*)&As_v[kk][ty << 2];
        *(float4*)aq = *(const float4*)&As_q[kk][ty << 2];
        *(float4*)at = *(const float4*)&As_t[kk][ty << 2];
        *(float4*)bv = *(const float4*)&Bs_v[kk][tx << 2];
        *(float4*)bq = *(const float4*)&Bs_q[kk][tx << 2];
        *(float4*)bt = *(const float4*)&Bs_t[kk][tx << 2];
        #pragma unroll
        for (int i = 0; i < 4; ++i) {
            #pragma unroll
            for (int j = 0; j < 4; ++j) {
                acc[i][j]  = fmaf(av[i] * bv[j], fminf(aq[i], bq[j]), acc[i][j]);
                acce[i][j] = fmaf(at[i], bt[j], acce[i][j]);
            }
        }
    }

    const int MN = MDIM * NDIM;
    #pragma unroll
    for (int i = 0; i < 4; ++i) {
        int m = m0 + (ty << 2) + i;
        #pragma unroll
        for (int j = 0; j < 4; ++j) {
            int n = n0 + (tx << 2) + j;
            unsafeAtomicAdd(&out[m * NDIM + n], acc[i][j]);
            unsafeAtomicAdd(&out[MN + m * NDIM + n], acce[i][j]);
        }
    }
}

extern "C" void kernel_launch(void* const* d_in, const int* in_sizes, int n_in,
                              void* d_out, int out_size, void* d_ws, size_t ws_size,
                              hipStream_t stream) {
    const float* t1 = (const float*)d_in[0];
    const float* t2 = (const float*)d_in[1];
    // d_in[2] = rngSeq (arange -> thermometer code), d_in[3] = dataWidth (cancels)
    int L = in_sizes[2];
    int logL = 31 - __builtin_clz((unsigned)L);

    float* out = (float*)d_out;
    hipMemsetAsync(out, 0, (size_t)out_size * sizeof(float), stream);

    hipLaunchKernelGGL(sc_gemm, dim3(NDIM / BN, MDIM / BM, KSPLIT), dim3(256), 0,
                       stream, t1, t2, out, (float)L, logL);
}

// Round 4
// 87.326 us; speedup vs baseline: 1.9231x; 1.9231x over previous
//
#include <hip/hip_runtime.h>
#include <math.h>

#define MDIM 512
#define NDIM 512
#define KDIM 512
#define MN (MDIM * NDIM)

#define BM 64
#define BN 64
#define BK 32
#define LSTR 68   // padded LDS row stride (floats); mult-of-4 keeps b128 reads 16B-aligned

// SC encoding collapses to: ax = m*2^e (frexp), q = floor(m*L),
// v = sign * 2^(e+shAdj) with shAdj = -log2(L) for A, 0 for B. dataWidth cancels.
// min(q1,q2) == thermometer AND-popcount (both sequences are thermometer codes).
__device__ __forceinline__ void sc_encode(float x, int shAdj, float Lf,
                                          float& v, float& q) {
    float ax = fabsf(x);
    v = 0.0f; q = 0.0f;
    if (ax > 0.0f) {
        int e;
        float m = frexpf(ax, &e);          // ax = m * 2^e, m in [0.5,1)
        q = floorf(m * Lf);                // exact: m*L is an exact f32 product
        v = ldexpf((x > 0.0f) ? 1.0f : -1.0f, e + shAdj);
    }
}

// Fused SC-encode + min-GEMM (approx) + f32 GEMM (exact).
// Grid (N/BN, M/BM, KS); block 256; 4x4 micro-tile.
// NO atomics: each z-slice writes its full 64x64x2 partial tile to
// dst + z*2*MN as streaming float4 stores (L2 write-back, not atomic
// write-through — R3 showed f32 atomics cost 16B of HBM write each).
template<int KS>
__global__ __launch_bounds__(256) void sc_gemm_k(
        const float* __restrict__ t1, const float* __restrict__ t2,
        float* __restrict__ dst, float Lf, int logL) {
    __shared__ __align__(16) float As_v[BK][LSTR];
    __shared__ __align__(16) float As_q[BK][LSTR];
    __shared__ __align__(16) float As_t[BK][LSTR];
    __shared__ __align__(16) float Bs_v[BK][LSTR];
    __shared__ __align__(16) float Bs_q[BK][LSTR];
    __shared__ __align__(16) float Bs_t[BK][LSTR];

    const int tid = threadIdx.x;
    const int tx = tid & 15;
    const int ty = tid >> 4;
    const int n0 = blockIdx.x * BN;
    const int m0 = blockIdx.y * BM;
    const int kbase = blockIdx.z * (KDIM / KS);

    float acc[4][4] = {};
    float acce[4][4] = {};

    for (int kt = 0; kt < (KDIM / KS) / BK; ++kt) {
        const int kk0 = kbase + kt * BK;
        if (kt) __syncthreads();

        // stage A tile (64 m-rows x 32 k), encode inline, transpose into LDS [k][m]
        #pragma unroll
        for (int ff = 0; ff < 2; ++ff) {
            int f = tid + ff * 256;            // 512 float4s
            int row = f >> 3;                  // 0..63
            int c4  = (f & 7) << 2;            // k offset 0..28
            float4 t = *(const float4*)(t1 + (m0 + row) * KDIM + kk0 + c4);
            const float* tp = &t.x;
            #pragma unroll
            for (int d = 0; d < 4; ++d) {
                float v, q;
                sc_encode(tp[d], -logL, Lf, v, q);
                As_v[c4 + d][row] = v;
                As_q[c4 + d][row] = q;
                As_t[c4 + d][row] = tp[d];
            }
        }
        // stage B tile (32 k x 64 n), encode inline, natural layout [k][n]
        #pragma unroll
        for (int ff = 0; ff < 2; ++ff) {
            int f = tid + ff * 256;
            int rowk = f >> 4;                 // 0..31
            int c4   = (f & 15) << 2;          // n offset 0..60
            float4 t = *(const float4*)(t2 + (kk0 + rowk) * NDIM + n0 + c4);
            float4 v4, q4;
            float* vp = &v4.x; float* qp = &q4.x; const float* tp = &t.x;
            #pragma unroll
            for (int d = 0; d < 4; ++d) sc_encode(tp[d], 0, Lf, vp[d], qp[d]);
            *(float4*)&Bs_v[rowk][c4] = v4;
            *(float4*)&Bs_q[rowk][c4] = q4;
            *(float4*)&Bs_t[rowk][c4] = t;
        }
        __syncthreads();

        #pragma unroll 8
        for (int kk = 0; kk < BK; ++kk) {
            float av[4], aq[4], at[4], bv[4], bq[4], bt[4];
            *(float4*)av = *(const float4*)&As_v[kk][ty << 2];
            *(float4*)aq = *(const float4*)&As_q[kk][ty << 2];
            *(float4*)at = *(const float4*)&As_t[kk][ty << 2];
            *(float4*)bv = *(const float4*)&Bs_v[kk][tx << 2];
            *(float4*)bq = *(const float4*)&Bs_q[kk][tx << 2];
            *(float4*)bt = *(const float4*)&Bs_t[kk][tx << 2];
            #pragma unroll
            for (int i = 0; i < 4; ++i) {
                #pragma unroll
                for (int j = 0; j < 4; ++j) {
                    acc[i][j]  = fmaf(av[i] * bv[j], fminf(aq[i], bq[j]), acc[i][j]);
                    acce[i][j] = fmaf(at[i], bt[j], acce[i][j]);
                }
            }
        }
    }

    // epilogue: streaming float4 partial stores (no atomics)
    float* o = dst + (size_t)blockIdx.z * (2 * MN);
    #pragma unroll
    for (int i = 0; i < 4; ++i) {
        int m = m0 + (ty << 2) + i;
        int nb = n0 + (tx << 2);
        float4 va = { acc[i][0],  acc[i][1],  acc[i][2],  acc[i][3] };
        float4 ve = { acce[i][0], acce[i][1], acce[i][2], acce[i][3] };
        *(float4*)&o[m * NDIM + nb]      = va;
        *(float4*)&o[MN + m * NDIM + nb] = ve;
    }
}

// Sum KS partial output images (each 2*MN floats) into d_out.
template<int KS>
__global__ __launch_bounds__(256) void reduce_k(const float4* __restrict__ ws,
                                                float4* __restrict__ out) {
    int i = blockIdx.x * blockDim.x + threadIdx.x;   // 0 .. 2*MN/4-1
    float4 s = ws[i];
    #pragma unroll
    for (int z = 1; z < KS; ++z) {
        float4 v = ws[(size_t)z * (2 * MN / 4) + i];
        s.x += v.x; s.y += v.y; s.z += v.z; s.w += v.w;
    }
    out[i] = s;
}

extern "C" void kernel_launch(void* const* d_in, const int* in_sizes, int n_in,
                              void* d_out, int out_size, void* d_ws, size_t ws_size,
                              hipStream_t stream) {
    const float* t1 = (const float*)d_in[0];
    const float* t2 = (const float*)d_in[1];
    // d_in[2] = rngSeq (arange -> thermometer code), d_in[3] = dataWidth (cancels)
    int L = in_sizes[2];
    int logL = 31 - __builtin_clz((unsigned)L);
    float Lf = (float)L;

    float* out = (float*)d_out;
    float* ws  = (float*)d_ws;
    const size_t perSplit = (size_t)2 * MN * sizeof(float);   // 2 MB
    const int nred = (2 * MN / 4) / 256;                      // 512 blocks

    if (ws_size >= 8 * perSplit) {
        hipLaunchKernelGGL((sc_gemm_k<8>), dim3(NDIM / BN, MDIM / BM, 8), dim3(256),
                           0, stream, t1, t2, ws, Lf, logL);
        hipLaunchKernelGGL((reduce_k<8>), dim3(nred), dim3(256), 0, stream,
                           (const float4*)ws, (float4*)out);
    } else if (ws_size >= 4 * perSplit) {
        hipLaunchKernelGGL((sc_gemm_k<4>), dim3(NDIM / BN, MDIM / BM, 4), dim3(256),
                           0, stream, t1, t2, ws, Lf, logL);
        hipLaunchKernelGGL((reduce_k<4>), dim3(nred), dim3(256), 0, stream,
                           (const float4*)ws, (float4*)out);
    } else if (ws_size >= 2 * perSplit) {
        hipLaunchKernelGGL((sc_gemm_k<2>), dim3(NDIM / BN, MDIM / BM, 2), dim3(256),
                           0, stream, t1, t2, ws, Lf, logL);
        hipLaunchKernelGGL((reduce_k<2>), dim3(nred), dim3(256), 0, stream,
                           (const float4*)ws, (float4*)out);
    } else {
        // no workspace: single-slice grid writes d_out directly (still no atomics)
        hipLaunchKernelGGL((sc_gemm_k<1>), dim3(NDIM / BN, MDIM / BM, 1), dim3(256),
                           0, stream, t1, t2, out, Lf, logL);
    }
}